// Round 8
// baseline (307.901 us; speedup 1.0000x reference)
//
#include <hip/hip_runtime.h>
#include <hip/hip_fp16.h>
#include <cstdint>

#define NEG_SLOPE 0.2f
#define EPSV 1e-16f

#define BIN_SHIFT 8
#define NODES_PER_BIN 256
#define MAXBINS 512
#define CHUNK 8192

// ---------------- Layer 1 GEMM: h1 = x@W1 (N,128)->(N,64) + alpha logits ----------------
// k-outer loop: W fragment loaded once from LDS, reused across 8 nodes (x reads broadcast).
__global__ __launch_bounds__(256) void gemm1_alpha(
    const float* __restrict__ x, const float* __restrict__ W1,
    const float* __restrict__ aS, const float* __restrict__ aD,
    __half* __restrict__ h1h, float* __restrict__ as1, float* __restrict__ ad1, int N)
{
    __shared__ float WsT[64 * 128];  // 32 KB, col-major + XOR-swizzled float4 chunks
    __shared__ float xs[32][128];    // 16 KB
    int t = threadIdx.x;
    for (int i = t; i < 128 * 64; i += 256) {
        int k = i >> 6, c = i & 63;
        WsT[c * 128 + (k ^ ((c & 7) << 2))] = W1[i];
    }
    int n0 = blockIdx.x * 32;
    for (int i = t; i < 32 * 128; i += 256) {
        int r = i >> 7, c = i & 127;
        int n = n0 + r;
        xs[r][c] = (n < N) ? x[(size_t)n * 128 + c] : 0.f;
    }
    __syncthreads();
    int wv = t >> 6;
    int col = t & 63;     // col = h*8 + d
    const float4* wrow = (const float4*)&WsT[col * 128];
    int sw = col & 7;
    float acc[8];
#pragma unroll
    for (int r = 0; r < 8; ++r) acc[r] = 0.f;
#pragma unroll 8
    for (int k4 = 0; k4 < 32; ++k4) {
        float4 w4 = wrow[k4 ^ sw];
#pragma unroll
        for (int r = 0; r < 8; ++r) {
            float4 x4 = ((const float4*)xs[wv * 8 + r])[k4];
            acc[r] = fmaf(x4.x, w4.x, acc[r]);
            acc[r] = fmaf(x4.y, w4.y, acc[r]);
            acc[r] = fmaf(x4.z, w4.z, acc[r]);
            acc[r] = fmaf(x4.w, w4.w, acc[r]);
        }
    }
    float asc = aS[col], adc = aD[col];
#pragma unroll
    for (int r = 0; r < 8; ++r) {
        int n = n0 + wv * 8 + r;
        float s = acc[r] * asc;
        float d = acc[r] * adc;
#pragma unroll
        for (int off = 1; off < 8; off <<= 1) {
            s += __shfl_xor(s, off, 64);
            d += __shfl_xor(d, off, 64);
        }
        if (n < N) {
            h1h[(size_t)n * 64 + col] = __float2half(acc[r]);
            if ((col & 7) == 0) {
                as1[n * 8 + (col >> 3)] = s;
                ad1[n * 8 + (col >> 3)] = d;
            }
        }
    }
}

// ---------------- CSR build: binned counting sort ----------------
__global__ __launch_bounds__(256) void binhist(
    const int* __restrict__ dsts, int* __restrict__ bincnt, int E, int Et, int nbins)
{
    __shared__ int lh[MAXBINS];
    int t = threadIdx.x;
    for (int i = t; i < nbins; i += 256) lh[i] = 0;
    __syncthreads();
    int base = blockIdx.x * CHUNK;
#pragma unroll
    for (int r = 0; r < CHUNK / 256; ++r) {
        int i = base + r * 256 + t;
        if (i < Et) {
            int dn = (i < E) ? dsts[i] : (i - E);
            atomicAdd(&lh[dn >> BIN_SHIFT], 1);
        }
    }
    __syncthreads();
    for (int i = t; i < nbins; i += 256)
        if (lh[i]) atomicAdd(&bincnt[i], lh[i]);
}

__global__ void binscan(const int* __restrict__ bincnt, int* __restrict__ binoff,
                        int* __restrict__ bincur, int* __restrict__ row_ptr,
                        int nbins, int N, int Et)
{
    if (threadIdx.x == 0 && blockIdx.x == 0) {
        int run = 0;
        for (int b = 0; b < nbins; ++b) { binoff[b] = run; bincur[b] = run; run += bincnt[b]; }
        binoff[nbins] = run;
        row_ptr[N] = Et;
    }
}

__global__ __launch_bounds__(256) void binscatter(
    const int* __restrict__ srcs, const int* __restrict__ dsts,
    int* __restrict__ bincur, unsigned int* __restrict__ binned, int E, int Et, int nbins)
{
    __shared__ int lh[MAXBINS];
    __shared__ int gbase[MAXBINS];
    __shared__ int lcur[MAXBINS];
    int t = threadIdx.x;
    for (int i = t; i < nbins; i += 256) lh[i] = 0;
    __syncthreads();
    int base = blockIdx.x * CHUNK;
#pragma unroll
    for (int r = 0; r < CHUNK / 256; ++r) {
        int i = base + r * 256 + t;
        if (i < Et) {
            int dn = (i < E) ? dsts[i] : (i - E);
            atomicAdd(&lh[dn >> BIN_SHIFT], 1);
        }
    }
    __syncthreads();
    for (int i = t; i < nbins; i += 256) {
        gbase[i] = lh[i] ? atomicAdd(&bincur[i], lh[i]) : 0;
        lcur[i] = 0;
    }
    __syncthreads();
#pragma unroll
    for (int r = 0; r < CHUNK / 256; ++r) {
        int i = base + r * 256 + t;
        if (i < Et) {
            int s, dn;
            if (i < E) { s = srcs[i]; dn = dsts[i]; }
            else       { s = i - E;   dn = s; }
            int b = dn >> BIN_SHIFT;
            int li = atomicAdd(&lcur[b], 1);
            binned[gbase[b] + li] = ((unsigned)(dn & (NODES_PER_BIN - 1)) << 24) | (unsigned)s;
        }
    }
}

__global__ __launch_bounds__(256) void binsort(
    const unsigned int* __restrict__ binned, const int* __restrict__ binoff,
    int* __restrict__ row_ptr, int* __restrict__ colx, int N, int nbins)
{
    __shared__ int lh[NODES_PER_BIN];
    __shared__ int lcur[NODES_PER_BIN];
    int b = blockIdx.x, t = threadIdx.x;
    int beg = binoff[b], end = binoff[b + 1];
    lh[t] = 0;
    __syncthreads();
    for (int j = beg + t; j < end; j += 256)
        atomicAdd(&lh[binned[j] >> 24], 1);
    __syncthreads();
    int own = lh[t];
    for (int off = 1; off < 256; off <<= 1) {
        int y = (t >= off) ? lh[t - off] : 0;
        __syncthreads();
        lh[t] += y;
        __syncthreads();
    }
    int excl = lh[t] - own;
    int gnode = (b << BIN_SHIFT) + t;
    if (gnode < N) row_ptr[gnode] = beg + excl;
    lcur[t] = excl;
    __syncthreads();
    for (int j = beg + t; j < end; j += 256) {
        unsigned p = binned[j];
        int pos = atomicAdd(&lcur[p >> 24], 1);
        colx[beg + pos] = (int)(p & 0xFFFFFF);
    }
}

// ---------------- Layer 1 gather: 2 edges/wave, uniform loop + predicated weights ----------------
__global__ __launch_bounds__(256) void gather1(
    const int* __restrict__ row_ptr, const int* __restrict__ colx,
    const float* __restrict__ as1, const float* __restrict__ ad1,
    const __half2* __restrict__ h1v, const float2* __restrict__ bias1,
    float2* __restrict__ helu, int N)
{
    int wave = (blockIdx.x * 256 + threadIdx.x) >> 6;
    if (wave >= N) return;
    int lane = threadIdx.x & 63;
    int half = lane >> 5;
    int sub = lane & 31;          // owns dims 2*sub, 2*sub+1
    int hh = sub >> 2;            // head of those dims
    int n = wave;
    float adn = ad1[n * 8 + hh];
    int beg = row_ptr[n], end = row_ptr[n + 1];
    float2 acc = make_float2(0.f, 0.f);
    float wsum = 0.f;
    for (int cb = beg; cb < end; cb += 64) {
        int cnt = min(64, end - cb);
        int sv = (cb + lane < end) ? colx[cb + lane] : 0;
        int iters = (cnt + 3) >> 2;   // uniform across wave
        for (int i = 0; i < iters; ++i) {
            int k0 = (i << 2) + half;
            int k1 = k0 + 2;
            int sA = __shfl(sv, k0, 64);   // all lanes active: defined
            int sB = __shfl(sv, k1, 64);   // OOB lanes hold sv=0 (valid node)
            float aA = as1[sA * 8 + hh];
            float aB = as1[sB * 8 + hh];
            __half2 hA = h1v[(size_t)sA * 32 + sub];
            __half2 hB = h1v[(size_t)sB * 32 + sub];
            float eA = aA + adn; eA = (eA > 0.f) ? eA : NEG_SLOPE * eA;
            float eB = aB + adn; eB = (eB > 0.f) ? eB : NEG_SLOPE * eB;
            float wA = (k0 < cnt) ? __expf(eA) : 0.f;
            float wB = (k1 < cnt) ? __expf(eB) : 0.f;
            float2 fA = __half22float2(hA);
            float2 fB = __half22float2(hB);
            acc.x = fmaf(wA, fA.x, acc.x);
            acc.y = fmaf(wA, fA.y, acc.y);
            acc.x = fmaf(wB, fB.x, acc.x);
            acc.y = fmaf(wB, fB.y, acc.y);
            wsum += wA + wB;
        }
    }
    acc.x += __shfl_xor(acc.x, 32, 64);
    acc.y += __shfl_xor(acc.y, 32, 64);
    wsum += __shfl_xor(wsum, 32, 64);
    if (half == 0) {
        float2 b = bias1[sub];
        float inv = 1.f / (wsum + EPSV);
        float vx = acc.x * inv + b.x;
        float vy = acc.y * inv + b.y;
        vx = (vx > 0.f) ? vx : (__expf(vx) - 1.f);
        vy = (vy > 0.f) ? vy : (__expf(vy) - 1.f);
        helu[(size_t)n * 32 + sub] = make_float2(vx, vy);
    }
}

// ---------------- Layer 2 GEMM: h2 = helu@W2 (N,64)->(N,40), k-outer + W hoist ----------------
__global__ __launch_bounds__(256) void gemm2_alpha(
    const float* __restrict__ helu, const float* __restrict__ W2,
    const float* __restrict__ aS, const float* __restrict__ aD,
    __half* __restrict__ h2h, float* __restrict__ as2, float* __restrict__ ad2, int N)
{
    __shared__ float WsT[40 * 64];   // 10 KB, WsT[c][k^swz(c)]
    __shared__ float xs[32][64];     // 8 KB
    int t = threadIdx.x;
    for (int i = t; i < 64 * 40; i += 256) {
        int k = i / 40, c = i - k * 40;
        WsT[c * 64 + (k ^ ((c & 7) << 2))] = W2[i];
    }
    int n0 = blockIdx.x * 32;
    for (int i = t; i < 32 * 64; i += 256) {
        int r = i >> 6, c = i & 63;
        int n = n0 + r;
        xs[r][c] = (n < N) ? helu[(size_t)n * 64 + c] : 0.f;
    }
    __syncthreads();
    int wv = t >> 6;
    int c = t & 63;
    bool act = (c < 40);
    const float4* wrow = (const float4*)&WsT[(act ? c : 0) * 64];
    int sw = c & 7;
    float acc[8];
#pragma unroll
    for (int r = 0; r < 8; ++r) acc[r] = 0.f;
#pragma unroll
    for (int k4 = 0; k4 < 16; ++k4) {
        float4 w4 = wrow[k4 ^ sw];
#pragma unroll
        for (int r = 0; r < 8; ++r) {
            float4 x4 = ((const float4*)xs[wv * 8 + r])[k4];
            acc[r] = fmaf(x4.x, w4.x, acc[r]);
            acc[r] = fmaf(x4.y, w4.y, acc[r]);
            acc[r] = fmaf(x4.z, w4.z, acc[r]);
            acc[r] = fmaf(x4.w, w4.w, acc[r]);
        }
    }
    float asc = act ? aS[c] : 0.f;
    float adc = act ? aD[c] : 0.f;
#pragma unroll
    for (int r = 0; r < 8; ++r) {
        int n = n0 + wv * 8 + r;
        float a = act ? acc[r] : 0.f;
        float s = a * asc;
        float d = a * adc;
#pragma unroll
        for (int off = 1; off < 64; off <<= 1) {
            s += __shfl_xor(s, off, 64);
            d += __shfl_xor(d, off, 64);
        }
        if (n < N) {
            if (act) h2h[(size_t)n * 40 + c] = __float2half(a);
            if (c == 0) { as2[n] = s; ad2[n] = d; }
        }
    }
}

// ---------------- Layer 2 gather: 2 edges/wave, uniform loop + predicated weights ----------------
__global__ __launch_bounds__(256) void gather2(
    const int* __restrict__ row_ptr, const int* __restrict__ colx,
    const float* __restrict__ as2, const float* __restrict__ ad2,
    const __half2* __restrict__ h2v, const float2* __restrict__ bias2,
    float2* __restrict__ out, int N)
{
    int wave = (blockIdx.x * 256 + threadIdx.x) >> 6;
    if (wave >= N) return;
    int lane = threadIdx.x & 63;
    int half = lane >> 5;
    int sub = lane & 31;          // owns dims 2*sub, 2*sub+1 (sub<20 active)
    bool act = (sub < 20);
    int n = wave;
    float adn = ad2[n];
    int beg = row_ptr[n], end = row_ptr[n + 1];
    float2 acc = make_float2(0.f, 0.f);
    float wsum = 0.f;
    int subc = act ? sub : 0;
    for (int cb = beg; cb < end; cb += 64) {
        int cnt = min(64, end - cb);
        int sv = (cb + lane < end) ? colx[cb + lane] : 0;
        int iters = (cnt + 3) >> 2;   // uniform across wave
        for (int i = 0; i < iters; ++i) {
            int k0 = (i << 2) + half;
            int k1 = k0 + 2;
            int sA = __shfl(sv, k0, 64);
            int sB = __shfl(sv, k1, 64);
            float aA = as2[sA], aB = as2[sB];
            __half2 hA = h2v[(size_t)sA * 20 + subc];
            __half2 hB = h2v[(size_t)sB * 20 + subc];
            float eA = aA + adn; eA = (eA > 0.f) ? eA : NEG_SLOPE * eA;
            float eB = aB + adn; eB = (eB > 0.f) ? eB : NEG_SLOPE * eB;
            float wA = (k0 < cnt) ? __expf(eA) : 0.f;
            float wB = (k1 < cnt) ? __expf(eB) : 0.f;
            float2 fA = __half22float2(hA);
            float2 fB = __half22float2(hB);
            acc.x = fmaf(wA, fA.x, acc.x);
            acc.y = fmaf(wA, fA.y, acc.y);
            acc.x = fmaf(wB, fB.x, acc.x);
            acc.y = fmaf(wB, fB.y, acc.y);
            wsum += wA + wB;
        }
    }
    acc.x += __shfl_xor(acc.x, 32, 64);
    acc.y += __shfl_xor(acc.y, 32, 64);
    wsum += __shfl_xor(wsum, 32, 64);
    if (half == 0 && act) {
        float2 b = bias2[sub];
        float inv = 1.f / (wsum + EPSV);
        out[(size_t)n * 20 + sub] = make_float2(acc.x * inv + b.x, acc.y * inv + b.y);
    }
}

extern "C" void kernel_launch(void* const* d_in, const int* in_sizes, int n_in,
                              void* d_out, int out_size, void* d_ws, size_t ws_size,
                              hipStream_t stream)
{
    const float* x   = (const float*)d_in[0];
    const int*   ei  = (const int*)d_in[1];
    const float* W1  = (const float*)d_in[3];
    const float* aS1 = (const float*)d_in[4];
    const float* aD1 = (const float*)d_in[5];
    const float* b1  = (const float*)d_in[6];
    const float* W2  = (const float*)d_in[7];
    const float* aS2 = (const float*)d_in[8];
    const float* aD2 = (const float*)d_in[9];
    const float* b2  = (const float*)d_in[10];

    int N  = in_sizes[0] / 128;
    int E  = in_sizes[1] / 2;
    int Et = E + N;
    int nbins = (N + NODES_PER_BIN - 1) >> BIN_SHIFT;

    // ---- workspace layout ----
    float* fws   = (float*)d_ws;
    float* as1   = fws;                        // N*8
    float* ad1   = as1  + (size_t)N * 8;       // N*8
    float* helu  = ad1  + (size_t)N * 8;       // N*64
    float* as2   = helu + (size_t)N * 64;      // N
    float* ad2   = as2  + (size_t)N;           // N
    __half* h1h  = (__half*)(ad2 + (size_t)N); // N*64 halves
    __half* h2h  = h1h + (size_t)N * 64;       // N*40 halves
    int*   iws     = (int*)(h2h + (size_t)N * 40);
    int*   row_ptr = iws;                      // N+1
    int*   bincnt  = row_ptr + N + 1;          // MAXBINS+1
    int*   binoff  = bincnt + MAXBINS + 1;     // MAXBINS+1
    int*   bincur  = binoff + MAXBINS + 1;     // MAXBINS
    unsigned int* binned = (unsigned int*)(bincur + MAXBINS);  // Et
    int*   colx    = (int*)(binned + Et);      // Et
    float* out     = (float*)d_out;

    const int* srcs = ei;
    const int* dsts = ei + E;

    int blocksA = (Et + CHUNK - 1) / CHUNK;

    // ---- CSR build (binned counting sort) ----
    hipMemsetAsync(bincnt, 0, (size_t)(MAXBINS + 1) * sizeof(int), stream);
    binhist<<<blocksA, 256, 0, stream>>>(dsts, bincnt, E, Et, nbins);
    binscan<<<1, 64, 0, stream>>>(bincnt, binoff, bincur, row_ptr, nbins, N, Et);
    binscatter<<<blocksA, 256, 0, stream>>>(srcs, dsts, bincur, binned, E, Et, nbins);
    binsort<<<nbins, 256, 0, stream>>>(binned, binoff, row_ptr, colx, N, nbins);

    // ---- Layer 1 ----
    gemm1_alpha<<<(N + 31) / 32, 256, 0, stream>>>(x, W1, aS1, aD1, h1h, as1, ad1, N);
    gather1<<<(N * 64 + 255) / 256, 256, 0, stream>>>(row_ptr, colx, as1, ad1,
        (const __half2*)h1h, (const float2*)b1, (float2*)helu, N);

    // ---- Layer 2 ----
    gemm2_alpha<<<(N + 31) / 32, 256, 0, stream>>>(helu, W2, aS2, aD2, h2h, as2, ad2, N);
    gather2<<<(N * 64 + 255) / 256, 256, 0, stream>>>(row_ptr, colx, as2, ad2,
        (const __half2*)h2h, (const float2*)b2, (float2*)out, N);
}

// Round 9
// 255.034 us; speedup vs baseline: 1.2073x; 1.2073x over previous
//
#include <hip/hip_runtime.h>
#include <hip/hip_fp16.h>
#include <cstdint>

#define NEG_SLOPE 0.2f
#define EPSV 1e-16f

#define BIN_SHIFT 8
#define NODES_PER_BIN 256
#define MAXBINS 512
#define CHUNK 8192

// ---------------- Layer 1 GEMM: h1 = x@W1 (N,128)->(N,64) + alpha logits ----------------
// k-outer with K-tiling: per 32-k tile preload w[8] (32 VGPR), sweep 8 nodes.
// #pragma unroll 1 on the tile loop bounds the live set (round-8 spill post-mortem).
__global__ __launch_bounds__(256) void gemm1_alpha(
    const float* __restrict__ x, const float* __restrict__ W1,
    const float* __restrict__ aS, const float* __restrict__ aD,
    __half* __restrict__ h1h, float* __restrict__ as1, float* __restrict__ ad1, int N)
{
    __shared__ float WsT[64 * 128];  // 32 KB, col-major + XOR-swizzled float4 chunks
    __shared__ float xs[32][128];    // 16 KB
    int t = threadIdx.x;
    for (int i = t; i < 128 * 64; i += 256) {
        int k = i >> 6, c = i & 63;
        WsT[c * 128 + (k ^ ((c & 7) << 2))] = W1[i];
    }
    int n0 = blockIdx.x * 32;
    for (int i = t; i < 32 * 128; i += 256) {
        int r = i >> 7, c = i & 127;
        int n = n0 + r;
        xs[r][c] = (n < N) ? x[(size_t)n * 128 + c] : 0.f;
    }
    __syncthreads();
    int wv = t >> 6;
    int col = t & 63;     // col = h*8 + d
    const float4* wrow = (const float4*)&WsT[col * 128];
    int sw = col & 7;
    float acc[8];
#pragma unroll
    for (int r = 0; r < 8; ++r) acc[r] = 0.f;
#pragma unroll 1
    for (int kt = 0; kt < 4; ++kt) {
        float4 w[8];
#pragma unroll
        for (int j = 0; j < 8; ++j) w[j] = wrow[(kt * 8 + j) ^ sw];
#pragma unroll
        for (int r = 0; r < 8; ++r) {
            const float4* xr = (const float4*)xs[wv * 8 + r];
            float a = acc[r];
#pragma unroll
            for (int j = 0; j < 8; ++j) {
                float4 x4 = xr[kt * 8 + j];
                a = fmaf(x4.x, w[j].x, a);
                a = fmaf(x4.y, w[j].y, a);
                a = fmaf(x4.z, w[j].z, a);
                a = fmaf(x4.w, w[j].w, a);
            }
            acc[r] = a;
        }
    }
    float asc = aS[col], adc = aD[col];
#pragma unroll
    for (int r = 0; r < 8; ++r) {
        int n = n0 + wv * 8 + r;
        float s = acc[r] * asc;
        float d = acc[r] * adc;
#pragma unroll
        for (int off = 1; off < 8; off <<= 1) {
            s += __shfl_xor(s, off, 64);
            d += __shfl_xor(d, off, 64);
        }
        if (n < N) {
            h1h[(size_t)n * 64 + col] = __float2half(acc[r]);
            if ((col & 7) == 0) {
                as1[n * 8 + (col >> 3)] = s;
                ad1[n * 8 + (col >> 3)] = d;
            }
        }
    }
}

// ---------------- CSR build: binned counting sort ----------------
__global__ __launch_bounds__(256) void binhist(
    const int* __restrict__ dsts, int* __restrict__ bincnt, int E, int Et, int nbins)
{
    __shared__ int lh[MAXBINS];
    int t = threadIdx.x;
    for (int i = t; i < nbins; i += 256) lh[i] = 0;
    __syncthreads();
    int base = blockIdx.x * CHUNK;
#pragma unroll
    for (int r = 0; r < CHUNK / 256; ++r) {
        int i = base + r * 256 + t;
        if (i < Et) {
            int dn = (i < E) ? dsts[i] : (i - E);
            atomicAdd(&lh[dn >> BIN_SHIFT], 1);
        }
    }
    __syncthreads();
    for (int i = t; i < nbins; i += 256)
        if (lh[i]) atomicAdd(&bincnt[i], lh[i]);
}

__global__ void binscan(const int* __restrict__ bincnt, int* __restrict__ binoff,
                        int* __restrict__ bincur, int* __restrict__ row_ptr,
                        int nbins, int N, int Et)
{
    if (threadIdx.x == 0 && blockIdx.x == 0) {
        int run = 0;
        for (int b = 0; b < nbins; ++b) { binoff[b] = run; bincur[b] = run; run += bincnt[b]; }
        binoff[nbins] = run;
        row_ptr[N] = Et;
    }
}

__global__ __launch_bounds__(256) void binscatter(
    const int* __restrict__ srcs, const int* __restrict__ dsts,
    int* __restrict__ bincur, unsigned int* __restrict__ binned, int E, int Et, int nbins)
{
    __shared__ int lh[MAXBINS];
    __shared__ int gbase[MAXBINS];
    __shared__ int lcur[MAXBINS];
    int t = threadIdx.x;
    for (int i = t; i < nbins; i += 256) lh[i] = 0;
    __syncthreads();
    int base = blockIdx.x * CHUNK;
#pragma unroll
    for (int r = 0; r < CHUNK / 256; ++r) {
        int i = base + r * 256 + t;
        if (i < Et) {
            int dn = (i < E) ? dsts[i] : (i - E);
            atomicAdd(&lh[dn >> BIN_SHIFT], 1);
        }
    }
    __syncthreads();
    for (int i = t; i < nbins; i += 256) {
        gbase[i] = lh[i] ? atomicAdd(&bincur[i], lh[i]) : 0;
        lcur[i] = 0;
    }
    __syncthreads();
#pragma unroll
    for (int r = 0; r < CHUNK / 256; ++r) {
        int i = base + r * 256 + t;
        if (i < Et) {
            int s, dn;
            if (i < E) { s = srcs[i]; dn = dsts[i]; }
            else       { s = i - E;   dn = s; }
            int b = dn >> BIN_SHIFT;
            int li = atomicAdd(&lcur[b], 1);
            binned[gbase[b] + li] = ((unsigned)(dn & (NODES_PER_BIN - 1)) << 24) | (unsigned)s;
        }
    }
}

__global__ __launch_bounds__(256) void binsort(
    const unsigned int* __restrict__ binned, const int* __restrict__ binoff,
    int* __restrict__ row_ptr, int* __restrict__ colx, int N, int nbins)
{
    __shared__ int lh[NODES_PER_BIN];
    __shared__ int lcur[NODES_PER_BIN];
    int b = blockIdx.x, t = threadIdx.x;
    int beg = binoff[b], end = binoff[b + 1];
    lh[t] = 0;
    __syncthreads();
    for (int j = beg + t; j < end; j += 256)
        atomicAdd(&lh[binned[j] >> 24], 1);
    __syncthreads();
    int own = lh[t];
    for (int off = 1; off < 256; off <<= 1) {
        int y = (t >= off) ? lh[t - off] : 0;
        __syncthreads();
        lh[t] += y;
        __syncthreads();
    }
    int excl = lh[t] - own;
    int gnode = (b << BIN_SHIFT) + t;
    if (gnode < N) row_ptr[gnode] = beg + excl;
    lcur[t] = excl;
    __syncthreads();
    for (int j = beg + t; j < end; j += 256) {
        unsigned p = binned[j];
        int pos = atomicAdd(&lcur[p >> 24], 1);
        colx[beg + pos] = (int)(p & 0xFFFFFF);
    }
}

// ---------------- Layer 1 gather: 2 edges/wave, uniform loop + predicated weights ----------------
__global__ __launch_bounds__(256) void gather1(
    const int* __restrict__ row_ptr, const int* __restrict__ colx,
    const float* __restrict__ as1, const float* __restrict__ ad1,
    const __half2* __restrict__ h1v, const float2* __restrict__ bias1,
    float2* __restrict__ helu, int N)
{
    int wave = (blockIdx.x * 256 + threadIdx.x) >> 6;
    if (wave >= N) return;
    int lane = threadIdx.x & 63;
    int half = lane >> 5;
    int sub = lane & 31;          // owns dims 2*sub, 2*sub+1
    int hh = sub >> 2;            // head of those dims
    int n = wave;
    float adn = ad1[n * 8 + hh];
    int beg = row_ptr[n], end = row_ptr[n + 1];
    float2 acc = make_float2(0.f, 0.f);
    float wsum = 0.f;
    for (int cb = beg; cb < end; cb += 64) {
        int cnt = min(64, end - cb);
        int sv = (cb + lane < end) ? colx[cb + lane] : 0;
        int iters = (cnt + 3) >> 2;   // uniform across wave
        for (int i = 0; i < iters; ++i) {
            int k0 = (i << 2) + half;
            int k1 = k0 + 2;
            int sA = __shfl(sv, k0, 64);   // all lanes active: defined
            int sB = __shfl(sv, k1, 64);   // OOB lanes hold sv=0 (valid node)
            float aA = as1[sA * 8 + hh];
            float aB = as1[sB * 8 + hh];
            __half2 hA = h1v[(size_t)sA * 32 + sub];
            __half2 hB = h1v[(size_t)sB * 32 + sub];
            float eA = aA + adn; eA = (eA > 0.f) ? eA : NEG_SLOPE * eA;
            float eB = aB + adn; eB = (eB > 0.f) ? eB : NEG_SLOPE * eB;
            float wA = (k0 < cnt) ? __expf(eA) : 0.f;
            float wB = (k1 < cnt) ? __expf(eB) : 0.f;
            float2 fA = __half22float2(hA);
            float2 fB = __half22float2(hB);
            acc.x = fmaf(wA, fA.x, acc.x);
            acc.y = fmaf(wA, fA.y, acc.y);
            acc.x = fmaf(wB, fB.x, acc.x);
            acc.y = fmaf(wB, fB.y, acc.y);
            wsum += wA + wB;
        }
    }
    acc.x += __shfl_xor(acc.x, 32, 64);
    acc.y += __shfl_xor(acc.y, 32, 64);
    wsum += __shfl_xor(wsum, 32, 64);
    if (half == 0) {
        float2 b = bias1[sub];
        float inv = 1.f / (wsum + EPSV);
        float vx = acc.x * inv + b.x;
        float vy = acc.y * inv + b.y;
        vx = (vx > 0.f) ? vx : (__expf(vx) - 1.f);
        vy = (vy > 0.f) ? vy : (__expf(vy) - 1.f);
        helu[(size_t)n * 32 + sub] = make_float2(vx, vy);
    }
}

// ---------------- Layer 2 GEMM: h2 = helu@W2 (N,64)->(N,40), K-tiled k-outer ----------------
__global__ __launch_bounds__(256) void gemm2_alpha(
    const float* __restrict__ helu, const float* __restrict__ W2,
    const float* __restrict__ aS, const float* __restrict__ aD,
    __half* __restrict__ h2h, float* __restrict__ as2, float* __restrict__ ad2, int N)
{
    __shared__ float WsT[40 * 64];   // 10 KB, WsT[c][k^swz(c)]
    __shared__ float xs[32][64];     // 8 KB
    int t = threadIdx.x;
    for (int i = t; i < 64 * 40; i += 256) {
        int k = i / 40, c = i - k * 40;
        WsT[c * 64 + (k ^ ((c & 7) << 2))] = W2[i];
    }
    int n0 = blockIdx.x * 32;
    for (int i = t; i < 32 * 64; i += 256) {
        int r = i >> 6, c = i & 63;
        int n = n0 + r;
        xs[r][c] = (n < N) ? helu[(size_t)n * 64 + c] : 0.f;
    }
    __syncthreads();
    int wv = t >> 6;
    int c = t & 63;
    bool act = (c < 40);
    const float4* wrow = (const float4*)&WsT[(act ? c : 0) * 64];
    int sw = c & 7;
    float acc[8];
#pragma unroll
    for (int r = 0; r < 8; ++r) acc[r] = 0.f;
#pragma unroll 1
    for (int kt = 0; kt < 2; ++kt) {
        float4 w[8];
#pragma unroll
        for (int j = 0; j < 8; ++j) w[j] = wrow[(kt * 8 + j) ^ sw];
#pragma unroll
        for (int r = 0; r < 8; ++r) {
            const float4* xr = (const float4*)xs[wv * 8 + r];
            float a = acc[r];
#pragma unroll
            for (int j = 0; j < 8; ++j) {
                float4 x4 = xr[kt * 8 + j];
                a = fmaf(x4.x, w[j].x, a);
                a = fmaf(x4.y, w[j].y, a);
                a = fmaf(x4.z, w[j].z, a);
                a = fmaf(x4.w, w[j].w, a);
            }
            acc[r] = a;
        }
    }
    float asc = act ? aS[c] : 0.f;
    float adc = act ? aD[c] : 0.f;
#pragma unroll
    for (int r = 0; r < 8; ++r) {
        int n = n0 + wv * 8 + r;
        float a = act ? acc[r] : 0.f;
        float s = a * asc;
        float d = a * adc;
#pragma unroll
        for (int off = 1; off < 64; off <<= 1) {
            s += __shfl_xor(s, off, 64);
            d += __shfl_xor(d, off, 64);
        }
        if (n < N) {
            if (act) h2h[(size_t)n * 40 + c] = __float2half(a);
            if (c == 0) { as2[n] = s; ad2[n] = d; }
        }
    }
}

// ---------------- Layer 2 gather: 2 edges/wave, uniform loop + predicated weights ----------------
__global__ __launch_bounds__(256) void gather2(
    const int* __restrict__ row_ptr, const int* __restrict__ colx,
    const float* __restrict__ as2, const float* __restrict__ ad2,
    const __half2* __restrict__ h2v, const float2* __restrict__ bias2,
    float2* __restrict__ out, int N)
{
    int wave = (blockIdx.x * 256 + threadIdx.x) >> 6;
    if (wave >= N) return;
    int lane = threadIdx.x & 63;
    int half = lane >> 5;
    int sub = lane & 31;          // owns dims 2*sub, 2*sub+1 (sub<20 active)
    bool act = (sub < 20);
    int n = wave;
    float adn = ad2[n];
    int beg = row_ptr[n], end = row_ptr[n + 1];
    float2 acc = make_float2(0.f, 0.f);
    float wsum = 0.f;
    int subc = act ? sub : 0;
    for (int cb = beg; cb < end; cb += 64) {
        int cnt = min(64, end - cb);
        int sv = (cb + lane < end) ? colx[cb + lane] : 0;
        int iters = (cnt + 3) >> 2;   // uniform across wave
        for (int i = 0; i < iters; ++i) {
            int k0 = (i << 2) + half;
            int k1 = k0 + 2;
            int sA = __shfl(sv, k0, 64);
            int sB = __shfl(sv, k1, 64);
            float aA = as2[sA], aB = as2[sB];
            __half2 hA = h2v[(size_t)sA * 20 + subc];
            __half2 hB = h2v[(size_t)sB * 20 + subc];
            float eA = aA + adn; eA = (eA > 0.f) ? eA : NEG_SLOPE * eA;
            float eB = aB + adn; eB = (eB > 0.f) ? eB : NEG_SLOPE * eB;
            float wA = (k0 < cnt) ? __expf(eA) : 0.f;
            float wB = (k1 < cnt) ? __expf(eB) : 0.f;
            float2 fA = __half22float2(hA);
            float2 fB = __half22float2(hB);
            acc.x = fmaf(wA, fA.x, acc.x);
            acc.y = fmaf(wA, fA.y, acc.y);
            acc.x = fmaf(wB, fB.x, acc.x);
            acc.y = fmaf(wB, fB.y, acc.y);
            wsum += wA + wB;
        }
    }
    acc.x += __shfl_xor(acc.x, 32, 64);
    acc.y += __shfl_xor(acc.y, 32, 64);
    wsum += __shfl_xor(wsum, 32, 64);
    if (half == 0 && act) {
        float2 b = bias2[sub];
        float inv = 1.f / (wsum + EPSV);
        out[(size_t)n * 20 + sub] = make_float2(acc.x * inv + b.x, acc.y * inv + b.y);
    }
}

extern "C" void kernel_launch(void* const* d_in, const int* in_sizes, int n_in,
                              void* d_out, int out_size, void* d_ws, size_t ws_size,
                              hipStream_t stream)
{
    const float* x   = (const float*)d_in[0];
    const int*   ei  = (const int*)d_in[1];
    const float* W1  = (const float*)d_in[3];
    const float* aS1 = (const float*)d_in[4];
    const float* aD1 = (const float*)d_in[5];
    const float* b1  = (const float*)d_in[6];
    const float* W2  = (const float*)d_in[7];
    const float* aS2 = (const float*)d_in[8];
    const float* aD2 = (const float*)d_in[9];
    const float* b2  = (const float*)d_in[10];

    int N  = in_sizes[0] / 128;
    int E  = in_sizes[1] / 2;
    int Et = E + N;
    int nbins = (N + NODES_PER_BIN - 1) >> BIN_SHIFT;

    // ---- workspace layout ----
    float* fws   = (float*)d_ws;
    float* as1   = fws;                        // N*8
    float* ad1   = as1  + (size_t)N * 8;       // N*8
    float* helu  = ad1  + (size_t)N * 8;       // N*64
    float* as2   = helu + (size_t)N * 64;      // N
    float* ad2   = as2  + (size_t)N;           // N
    __half* h1h  = (__half*)(ad2 + (size_t)N); // N*64 halves
    __half* h2h  = h1h + (size_t)N * 64;       // N*40 halves
    int*   iws     = (int*)(h2h + (size_t)N * 40);
    int*   row_ptr = iws;                      // N+1
    int*   bincnt  = row_ptr + N + 1;          // MAXBINS+1
    int*   binoff  = bincnt + MAXBINS + 1;     // MAXBINS+1
    int*   bincur  = binoff + MAXBINS + 1;     // MAXBINS
    unsigned int* binned = (unsigned int*)(bincur + MAXBINS);  // Et
    int*   colx    = (int*)(binned + Et);      // Et
    float* out     = (float*)d_out;

    const int* srcs = ei;
    const int* dsts = ei + E;

    int blocksA = (Et + CHUNK - 1) / CHUNK;

    // ---- CSR build (binned counting sort) ----
    hipMemsetAsync(bincnt, 0, (size_t)(MAXBINS + 1) * sizeof(int), stream);
    binhist<<<blocksA, 256, 0, stream>>>(dsts, bincnt, E, Et, nbins);
    binscan<<<1, 64, 0, stream>>>(bincnt, binoff, bincur, row_ptr, nbins, N, Et);
    binscatter<<<blocksA, 256, 0, stream>>>(srcs, dsts, bincur, binned, E, Et, nbins);
    binsort<<<nbins, 256, 0, stream>>>(binned, binoff, row_ptr, colx, N, nbins);

    // ---- Layer 1 ----
    gemm1_alpha<<<(N + 31) / 32, 256, 0, stream>>>(x, W1, aS1, aD1, h1h, as1, ad1, N);
    gather1<<<(N * 64 + 255) / 256, 256, 0, stream>>>(row_ptr, colx, as1, ad1,
        (const __half2*)h1h, (const float2*)b1, (float2*)helu, N);

    // ---- Layer 2 ----
    gemm2_alpha<<<(N + 31) / 32, 256, 0, stream>>>(helu, W2, aS2, aD2, h2h, as2, ad2, N);
    gather2<<<(N * 64 + 255) / 256, 256, 0, stream>>>(row_ptr, colx, as2, ad2,
        (const __half2*)h2h, (const float2*)b2, (float2*)out, N);
}

// Round 10
// 202.566 us; speedup vs baseline: 1.5200x; 1.2590x over previous
//
#include <hip/hip_runtime.h>
#include <hip/hip_fp16.h>
#include <cstdint>

#define NEG_SLOPE 0.2f
#define EPSV 1e-16f

#define BIN_SHIFT 8
#define NODES_PER_BIN 256
#define MAXBINS 512
#define CHUNK 8192

typedef _Float16 half8v __attribute__((ext_vector_type(8)));
typedef float float4v __attribute__((ext_vector_type(4)));

// ---------------- Layer 1 GEMM via MFMA: h1 = x@W1 (N,128)->(N,64) + alpha logits ----------------
// 64 nodes/block, 4 waves x 16 rows. fp16 operands staged in LDS with XOR swizzle.
__global__ __launch_bounds__(256) void gemm1_alpha(
    const float* __restrict__ x, const float* __restrict__ W1,
    const float* __restrict__ aS, const float* __restrict__ aD,
    __half* __restrict__ h1h, float* __restrict__ as1, float* __restrict__ ad1, int N)
{
    __shared__ _Float16 xh[64 * 128];   // 16 KB, xh[n][k] swizzled
    __shared__ _Float16 wt[64 * 128];   // 16 KB, wt[c][k] swizzled (W transposed)
    int t = threadIdx.x;
    int n0 = blockIdx.x * 64;

    // stage x -> fp16 (pairs, coalesced float2 reads)
    const float2* x2 = (const float2*)x;
#pragma unroll
    for (int i = 0; i < 16; ++i) {
        int p = t + i * 256;            // pair index over 64*64
        int n = p >> 6, kp = p & 63;
        int gn = n0 + n;
        float2 v = (gn < N) ? x2[(size_t)gn * 64 + kp] : make_float2(0.f, 0.f);
        union { _Float16 h[2]; uint32_t u; } cv;
        cv.h[0] = (_Float16)v.x; cv.h[1] = (_Float16)v.y;
        *(uint32_t*)&xh[n * 128 + ((kp * 2) ^ ((n & 7) << 3))] = cv.u;
    }
    // stage W1 (128x64) -> wt[c][k] fp16 (coalesced read, scattered u16 LDS write)
#pragma unroll
    for (int i = 0; i < 32; ++i) {
        int p = t + i * 256;            // over 8192
        int k = p >> 6, c = p & 63;
        wt[c * 128 + (k ^ ((c & 7) << 3))] = (_Float16)W1[p];
    }
    __syncthreads();

    int wv = t >> 6, l = t & 63;
    int m0 = wv * 16;
    int lr = l & 15;
    int lg = l >> 4;
    float4v acc[4];
#pragma unroll
    for (int ct = 0; ct < 4; ++ct) acc[ct] = (float4v)(0.f);
#pragma unroll
    for (int kt = 0; kt < 4; ++kt) {
        int kh0 = kt * 32 + lg * 8;
        int an = m0 + lr;
        half8v aF = *(half8v*)&xh[an * 128 + (kh0 ^ ((an & 7) << 3))];
#pragma unroll
        for (int ct = 0; ct < 4; ++ct) {
            int c = ct * 16 + lr;
            half8v bF = *(half8v*)&wt[c * 128 + (kh0 ^ ((c & 7) << 3))];
            acc[ct] = __builtin_amdgcn_mfma_f32_16x16x32_f16(aF, bF, acc[ct], 0, 0, 0);
        }
    }
    // epilogue: store h (fp16) + per-head alpha logits
#pragma unroll
    for (int ct = 0; ct < 4; ++ct) {
        int c = ct * 16 + lr;
        float asc = aS[c], adc = aD[c];
#pragma unroll
        for (int i = 0; i < 4; ++i) {
            int n = n0 + m0 + lg * 4 + i;
            float v = acc[ct][i];
            float s = v * asc, d = v * adc;
            s += __shfl_xor(s, 1, 64); s += __shfl_xor(s, 2, 64); s += __shfl_xor(s, 4, 64);
            d += __shfl_xor(d, 1, 64); d += __shfl_xor(d, 2, 64); d += __shfl_xor(d, 4, 64);
            if (n < N) {
                h1h[(size_t)n * 64 + c] = __float2half(v);
                if ((l & 7) == 0) {
                    int hd = 2 * ct + ((l >> 3) & 1);
                    as1[n * 8 + hd] = s;
                    ad1[n * 8 + hd] = d;
                }
            }
        }
    }
}

// ---------------- CSR build: binned counting sort ----------------
__global__ __launch_bounds__(256) void binhist(
    const int* __restrict__ dsts, int* __restrict__ bincnt, int E, int Et, int nbins)
{
    __shared__ int lh[MAXBINS];
    int t = threadIdx.x;
    for (int i = t; i < nbins; i += 256) lh[i] = 0;
    __syncthreads();
    int base = blockIdx.x * CHUNK;
#pragma unroll
    for (int r = 0; r < CHUNK / 256; ++r) {
        int i = base + r * 256 + t;
        if (i < Et) {
            int dn = (i < E) ? dsts[i] : (i - E);
            atomicAdd(&lh[dn >> BIN_SHIFT], 1);
        }
    }
    __syncthreads();
    for (int i = t; i < nbins; i += 256)
        if (lh[i]) atomicAdd(&bincnt[i], lh[i]);
}

__global__ void binscan(const int* __restrict__ bincnt, int* __restrict__ binoff,
                        int* __restrict__ bincur, int* __restrict__ row_ptr,
                        int nbins, int N, int Et)
{
    if (threadIdx.x == 0 && blockIdx.x == 0) {
        int run = 0;
        for (int b = 0; b < nbins; ++b) { binoff[b] = run; bincur[b] = run; run += bincnt[b]; }
        binoff[nbins] = run;
        row_ptr[N] = Et;
    }
}

__global__ __launch_bounds__(256) void binscatter(
    const int* __restrict__ srcs, const int* __restrict__ dsts,
    int* __restrict__ bincur, unsigned int* __restrict__ binned, int E, int Et, int nbins)
{
    __shared__ int lh[MAXBINS];
    __shared__ int gbase[MAXBINS];
    __shared__ int lcur[MAXBINS];
    int t = threadIdx.x;
    for (int i = t; i < nbins; i += 256) lh[i] = 0;
    __syncthreads();
    int base = blockIdx.x * CHUNK;
#pragma unroll
    for (int r = 0; r < CHUNK / 256; ++r) {
        int i = base + r * 256 + t;
        if (i < Et) {
            int dn = (i < E) ? dsts[i] : (i - E);
            atomicAdd(&lh[dn >> BIN_SHIFT], 1);
        }
    }
    __syncthreads();
    for (int i = t; i < nbins; i += 256) {
        gbase[i] = lh[i] ? atomicAdd(&bincur[i], lh[i]) : 0;
        lcur[i] = 0;
    }
    __syncthreads();
#pragma unroll
    for (int r = 0; r < CHUNK / 256; ++r) {
        int i = base + r * 256 + t;
        if (i < Et) {
            int s, dn;
            if (i < E) { s = srcs[i]; dn = dsts[i]; }
            else       { s = i - E;   dn = s; }
            int b = dn >> BIN_SHIFT;
            int li = atomicAdd(&lcur[b], 1);
            binned[gbase[b] + li] = ((unsigned)(dn & (NODES_PER_BIN - 1)) << 24) | (unsigned)s;
        }
    }
}

__global__ __launch_bounds__(256) void binsort(
    const unsigned int* __restrict__ binned, const int* __restrict__ binoff,
    int* __restrict__ row_ptr, int* __restrict__ colx, int N, int nbins)
{
    __shared__ int lh[NODES_PER_BIN];
    __shared__ int lcur[NODES_PER_BIN];
    int b = blockIdx.x, t = threadIdx.x;
    int beg = binoff[b], end = binoff[b + 1];
    lh[t] = 0;
    __syncthreads();
    for (int j = beg + t; j < end; j += 256)
        atomicAdd(&lh[binned[j] >> 24], 1);
    __syncthreads();
    int own = lh[t];
    for (int off = 1; off < 256; off <<= 1) {
        int y = (t >= off) ? lh[t - off] : 0;
        __syncthreads();
        lh[t] += y;
        __syncthreads();
    }
    int excl = lh[t] - own;
    int gnode = (b << BIN_SHIFT) + t;
    if (gnode < N) row_ptr[gnode] = beg + excl;
    lcur[t] = excl;
    __syncthreads();
    for (int j = beg + t; j < end; j += 256) {
        unsigned p = binned[j];
        int pos = atomicAdd(&lcur[p >> 24], 1);
        colx[beg + pos] = (int)(p & 0xFFFFFF);
    }
}

// ---------------- Layer 1 gather: 2 edges/wave, uniform loop + predicated weights ----------------
__global__ __launch_bounds__(256) void gather1(
    const int* __restrict__ row_ptr, const int* __restrict__ colx,
    const float* __restrict__ as1, const float* __restrict__ ad1,
    const __half2* __restrict__ h1v, const float2* __restrict__ bias1,
    float2* __restrict__ helu, int N)
{
    int wave = (blockIdx.x * 256 + threadIdx.x) >> 6;
    if (wave >= N) return;
    int lane = threadIdx.x & 63;
    int half = lane >> 5;
    int sub = lane & 31;          // owns dims 2*sub, 2*sub+1
    int hh = sub >> 2;            // head of those dims
    int n = wave;
    float adn = ad1[n * 8 + hh];
    int beg = row_ptr[n], end = row_ptr[n + 1];
    float2 acc = make_float2(0.f, 0.f);
    float wsum = 0.f;
    for (int cb = beg; cb < end; cb += 64) {
        int cnt = min(64, end - cb);
        int sv = (cb + lane < end) ? colx[cb + lane] : 0;
        int iters = (cnt + 3) >> 2;   // uniform across wave
        for (int i = 0; i < iters; ++i) {
            int k0 = (i << 2) + half;
            int k1 = k0 + 2;
            int sA = __shfl(sv, k0, 64);   // all lanes active: defined
            int sB = __shfl(sv, k1, 64);   // OOB lanes hold sv=0 (valid node)
            float aA = as1[sA * 8 + hh];
            float aB = as1[sB * 8 + hh];
            __half2 hA = h1v[(size_t)sA * 32 + sub];
            __half2 hB = h1v[(size_t)sB * 32 + sub];
            float eA = aA + adn; eA = (eA > 0.f) ? eA : NEG_SLOPE * eA;
            float eB = aB + adn; eB = (eB > 0.f) ? eB : NEG_SLOPE * eB;
            float wA = (k0 < cnt) ? __expf(eA) : 0.f;
            float wB = (k1 < cnt) ? __expf(eB) : 0.f;
            float2 fA = __half22float2(hA);
            float2 fB = __half22float2(hB);
            acc.x = fmaf(wA, fA.x, acc.x);
            acc.y = fmaf(wA, fA.y, acc.y);
            acc.x = fmaf(wB, fB.x, acc.x);
            acc.y = fmaf(wB, fB.y, acc.y);
            wsum += wA + wB;
        }
    }
    acc.x += __shfl_xor(acc.x, 32, 64);
    acc.y += __shfl_xor(acc.y, 32, 64);
    wsum += __shfl_xor(wsum, 32, 64);
    if (half == 0) {
        float2 b = bias1[sub];
        float inv = 1.f / (wsum + EPSV);
        float vx = acc.x * inv + b.x;
        float vy = acc.y * inv + b.y;
        vx = (vx > 0.f) ? vx : (__expf(vx) - 1.f);
        vy = (vy > 0.f) ? vy : (__expf(vy) - 1.f);
        helu[(size_t)n * 32 + sub] = make_float2(vx, vy);
    }
}

// ---------------- Layer 2 GEMM via MFMA: h2 = helu@W2 (N,64)->(N,40) + scalar alphas ----------------
__global__ __launch_bounds__(256) void gemm2_alpha(
    const float* __restrict__ helu, const float* __restrict__ W2,
    const float* __restrict__ aS, const float* __restrict__ aD,
    __half* __restrict__ h2h, float* __restrict__ as2, float* __restrict__ ad2, int N)
{
    __shared__ _Float16 xh[64 * 64];    // 8 KB
    __shared__ _Float16 wt[48 * 64];    // 6 KB (rows 40..47 zero)
    int t = threadIdx.x;
    int n0 = blockIdx.x * 64;

    // zero wt (covers pad rows)
    for (int i = t; i < (48 * 64) / 2; i += 256) ((uint32_t*)wt)[i] = 0;
    __syncthreads();

    // stage helu -> fp16
    const float2* h2p = (const float2*)helu;
#pragma unroll
    for (int i = 0; i < 8; ++i) {
        int p = t + i * 256;            // pairs over 64*32
        int n = p >> 5, kp = p & 31;
        int gn = n0 + n;
        float2 v = (gn < N) ? h2p[(size_t)gn * 32 + kp] : make_float2(0.f, 0.f);
        union { _Float16 h[2]; uint32_t u; } cv;
        cv.h[0] = (_Float16)v.x; cv.h[1] = (_Float16)v.y;
        *(uint32_t*)&xh[n * 64 + ((kp * 2) ^ ((n & 7) << 3))] = cv.u;
    }
    // stage W2 (64x40) -> wt[c][k]
#pragma unroll
    for (int i = 0; i < 10; ++i) {
        int p = t + i * 256;
        if (p < 64 * 40) {
            int k = p / 40, c = p - k * 40;
            wt[c * 64 + (k ^ ((c & 7) << 3))] = (_Float16)W2[p];
        }
    }
    __syncthreads();

    int wv = t >> 6, l = t & 63;
    int m0 = wv * 16;
    int lr = l & 15;
    int lg = l >> 4;
    float4v acc[3];
#pragma unroll
    for (int ct = 0; ct < 3; ++ct) acc[ct] = (float4v)(0.f);
#pragma unroll
    for (int kt = 0; kt < 2; ++kt) {
        int kh0 = kt * 32 + lg * 8;
        int an = m0 + lr;
        half8v aF = *(half8v*)&xh[an * 64 + (kh0 ^ ((an & 7) << 3))];
#pragma unroll
        for (int ct = 0; ct < 3; ++ct) {
            int c = ct * 16 + lr;
            half8v bF = *(half8v*)&wt[c * 64 + (kh0 ^ ((c & 7) << 3))];
            acc[ct] = __builtin_amdgcn_mfma_f32_16x16x32_f16(aF, bF, acc[ct], 0, 0, 0);
        }
    }
    // epilogue: h2h store (c<40) + scalar alpha reduce over 16 lanes
    float sv[4] = {0.f, 0.f, 0.f, 0.f};
    float dv[4] = {0.f, 0.f, 0.f, 0.f};
#pragma unroll
    for (int ct = 0; ct < 3; ++ct) {
        int c = ct * 16 + lr;
        bool av = (c < 40);
        float asc = av ? aS[c] : 0.f;
        float adc = av ? aD[c] : 0.f;
#pragma unroll
        for (int i = 0; i < 4; ++i) {
            int n = n0 + m0 + lg * 4 + i;
            float v = acc[ct][i];
            sv[i] = fmaf(v, asc, sv[i]);
            dv[i] = fmaf(v, adc, dv[i]);
            if (av && n < N) h2h[(size_t)n * 40 + c] = __float2half(v);
        }
    }
#pragma unroll
    for (int i = 0; i < 4; ++i) {
        float s = sv[i], d = dv[i];
        s += __shfl_xor(s, 1, 64); s += __shfl_xor(s, 2, 64);
        s += __shfl_xor(s, 4, 64); s += __shfl_xor(s, 8, 64);
        d += __shfl_xor(d, 1, 64); d += __shfl_xor(d, 2, 64);
        d += __shfl_xor(d, 4, 64); d += __shfl_xor(d, 8, 64);
        int n = n0 + m0 + lg * 4 + i;
        if (lr == 0 && n < N) { as2[n] = s; ad2[n] = d; }
    }
}

// ---------------- Layer 2 gather: 2 edges/wave, uniform loop + predicated weights ----------------
__global__ __launch_bounds__(256) void gather2(
    const int* __restrict__ row_ptr, const int* __restrict__ colx,
    const float* __restrict__ as2, const float* __restrict__ ad2,
    const __half2* __restrict__ h2v, const float2* __restrict__ bias2,
    float2* __restrict__ out, int N)
{
    int wave = (blockIdx.x * 256 + threadIdx.x) >> 6;
    if (wave >= N) return;
    int lane = threadIdx.x & 63;
    int half = lane >> 5;
    int sub = lane & 31;          // owns dims 2*sub, 2*sub+1 (sub<20 active)
    bool act = (sub < 20);
    int n = wave;
    float adn = ad2[n];
    int beg = row_ptr[n], end = row_ptr[n + 1];
    float2 acc = make_float2(0.f, 0.f);
    float wsum = 0.f;
    int subc = act ? sub : 0;
    for (int cb = beg; cb < end; cb += 64) {
        int cnt = min(64, end - cb);
        int sv = (cb + lane < end) ? colx[cb + lane] : 0;
        int iters = (cnt + 3) >> 2;   // uniform across wave
        for (int i = 0; i < iters; ++i) {
            int k0 = (i << 2) + half;
            int k1 = k0 + 2;
            int sA = __shfl(sv, k0, 64);
            int sB = __shfl(sv, k1, 64);
            float aA = as2[sA], aB = as2[sB];
            __half2 hA = h2v[(size_t)sA * 20 + subc];
            __half2 hB = h2v[(size_t)sB * 20 + subc];
            float eA = aA + adn; eA = (eA > 0.f) ? eA : NEG_SLOPE * eA;
            float eB = aB + adn; eB = (eB > 0.f) ? eB : NEG_SLOPE * eB;
            float wA = (k0 < cnt) ? __expf(eA) : 0.f;
            float wB = (k1 < cnt) ? __expf(eB) : 0.f;
            float2 fA = __half22float2(hA);
            float2 fB = __half22float2(hB);
            acc.x = fmaf(wA, fA.x, acc.x);
            acc.y = fmaf(wA, fA.y, acc.y);
            acc.x = fmaf(wB, fB.x, acc.x);
            acc.y = fmaf(wB, fB.y, acc.y);
            wsum += wA + wB;
        }
    }
    acc.x += __shfl_xor(acc.x, 32, 64);
    acc.y += __shfl_xor(acc.y, 32, 64);
    wsum += __shfl_xor(wsum, 32, 64);
    if (half == 0 && act) {
        float2 b = bias2[sub];
        float inv = 1.f / (wsum + EPSV);
        out[(size_t)n * 20 + sub] = make_float2(acc.x * inv + b.x, acc.y * inv + b.y);
    }
}

extern "C" void kernel_launch(void* const* d_in, const int* in_sizes, int n_in,
                              void* d_out, int out_size, void* d_ws, size_t ws_size,
                              hipStream_t stream)
{
    const float* x   = (const float*)d_in[0];
    const int*   ei  = (const int*)d_in[1];
    const float* W1  = (const float*)d_in[3];
    const float* aS1 = (const float*)d_in[4];
    const float* aD1 = (const float*)d_in[5];
    const float* b1  = (const float*)d_in[6];
    const float* W2  = (const float*)d_in[7];
    const float* aS2 = (const float*)d_in[8];
    const float* aD2 = (const float*)d_in[9];
    const float* b2  = (const float*)d_in[10];

    int N  = in_sizes[0] / 128;
    int E  = in_sizes[1] / 2;
    int Et = E + N;
    int nbins = (N + NODES_PER_BIN - 1) >> BIN_SHIFT;

    // ---- workspace layout ----
    float* fws   = (float*)d_ws;
    float* as1   = fws;                        // N*8
    float* ad1   = as1  + (size_t)N * 8;       // N*8
    float* helu  = ad1  + (size_t)N * 8;       // N*64
    float* as2   = helu + (size_t)N * 64;      // N
    float* ad2   = as2  + (size_t)N;           // N
    __half* h1h  = (__half*)(ad2 + (size_t)N); // N*64 halves
    __half* h2h  = h1h + (size_t)N * 64;       // N*40 halves
    int*   iws     = (int*)(h2h + (size_t)N * 40);
    int*   row_ptr = iws;                      // N+1
    int*   bincnt  = row_ptr + N + 1;          // MAXBINS+1
    int*   binoff  = bincnt + MAXBINS + 1;     // MAXBINS+1
    int*   bincur  = binoff + MAXBINS + 1;     // MAXBINS
    unsigned int* binned = (unsigned int*)(bincur + MAXBINS);  // Et
    int*   colx    = (int*)(binned + Et);      // Et
    float* out     = (float*)d_out;

    const int* srcs = ei;
    const int* dsts = ei + E;

    int blocksA = (Et + CHUNK - 1) / CHUNK;

    // ---- CSR build (binned counting sort) ----
    hipMemsetAsync(bincnt, 0, (size_t)(MAXBINS + 1) * sizeof(int), stream);
    binhist<<<blocksA, 256, 0, stream>>>(dsts, bincnt, E, Et, nbins);
    binscan<<<1, 64, 0, stream>>>(bincnt, binoff, bincur, row_ptr, nbins, N, Et);
    binscatter<<<blocksA, 256, 0, stream>>>(srcs, dsts, bincur, binned, E, Et, nbins);
    binsort<<<nbins, 256, 0, stream>>>(binned, binoff, row_ptr, colx, N, nbins);

    // ---- Layer 1 ----
    gemm1_alpha<<<(N + 63) / 64, 256, 0, stream>>>(x, W1, aS1, aD1, h1h, as1, ad1, N);
    gather1<<<(N * 64 + 255) / 256, 256, 0, stream>>>(row_ptr, colx, as1, ad1,
        (const __half2*)h1h, (const float2*)b1, (float2*)helu, N);

    // ---- Layer 2 ----
    gemm2_alpha<<<(N + 63) / 64, 256, 0, stream>>>(helu, W2, aS2, aD2, h2h, as2, ad2, N);
    gather2<<<(N * 64 + 255) / 256, 256, 0, stream>>>(row_ptr, colx, as2, ad2,
        (const __half2*)h2h, (const float2*)b2, (float2*)out, N);
}

// Round 11
// 201.218 us; speedup vs baseline: 1.5302x; 1.0067x over previous
//
#include <hip/hip_runtime.h>
#include <hip/hip_fp16.h>
#include <cstdint>

#define NEG_SLOPE 0.2f
#define EPSV 1e-16f

#define BIN_SHIFT 8
#define NODES_PER_BIN 256
#define MAXBINS 512
#define CHUNK 16384

typedef _Float16 half8v __attribute__((ext_vector_type(8)));
typedef float float4v __attribute__((ext_vector_type(4)));
typedef int v4i __attribute__((ext_vector_type(4)));

// CK-style raw buffer load intrinsics (32-bit voffset addressing, HW bounds check)
__device__ float buf_load_f32(v4i rsrc, int voffset, int soffset, int aux) __asm("llvm.amdgcn.raw.buffer.load.f32");
__device__ int   buf_load_i32(v4i rsrc, int voffset, int soffset, int aux) __asm("llvm.amdgcn.raw.buffer.load.i32");

__device__ inline v4i make_rsrc(const void* p, unsigned bytes) {
    union { v4i v; struct { const void* p; unsigned range; unsigned cfg; } s; } u;
    u.s.p = p; u.s.range = bytes; u.s.cfg = 0x00020000u;  // raw dword, gfx9 config
    return u.v;
}

// ---------------- Layer 1 GEMM via MFMA: h1 = x@W1 (N,128)->(N,64) + alpha logits ----------------
__global__ __launch_bounds__(256) void gemm1_alpha(
    const float* __restrict__ x, const float* __restrict__ W1,
    const float* __restrict__ aS, const float* __restrict__ aD,
    __half* __restrict__ h1h, float* __restrict__ as1, float* __restrict__ ad1, int N)
{
    __shared__ _Float16 xh[64 * 128];   // 16 KB, xh[n][k] swizzled
    __shared__ _Float16 wt[64 * 128];   // 16 KB, wt[c][k] swizzled (W transposed)
    int t = threadIdx.x;
    int n0 = blockIdx.x * 64;

    const float2* x2 = (const float2*)x;
#pragma unroll
    for (int i = 0; i < 16; ++i) {
        int p = t + i * 256;            // pair index over 64*64
        int n = p >> 6, kp = p & 63;
        int gn = n0 + n;
        float2 v = (gn < N) ? x2[(size_t)gn * 64 + kp] : make_float2(0.f, 0.f);
        union { _Float16 h[2]; uint32_t u; } cv;
        cv.h[0] = (_Float16)v.x; cv.h[1] = (_Float16)v.y;
        *(uint32_t*)&xh[n * 128 + ((kp * 2) ^ ((n & 7) << 3))] = cv.u;
    }
#pragma unroll
    for (int i = 0; i < 32; ++i) {
        int p = t + i * 256;            // over 8192
        int k = p >> 6, c = p & 63;
        wt[c * 128 + (k ^ ((c & 7) << 3))] = (_Float16)W1[p];
    }
    __syncthreads();

    int wv = t >> 6, l = t & 63;
    int m0 = wv * 16;
    int lr = l & 15;
    int lg = l >> 4;
    float4v acc[4];
#pragma unroll
    for (int ct = 0; ct < 4; ++ct) acc[ct] = (float4v)(0.f);
#pragma unroll
    for (int kt = 0; kt < 4; ++kt) {
        int kh0 = kt * 32 + lg * 8;
        int an = m0 + lr;
        half8v aF = *(half8v*)&xh[an * 128 + (kh0 ^ ((an & 7) << 3))];
#pragma unroll
        for (int ct = 0; ct < 4; ++ct) {
            int c = ct * 16 + lr;
            half8v bF = *(half8v*)&wt[c * 128 + (kh0 ^ ((c & 7) << 3))];
            acc[ct] = __builtin_amdgcn_mfma_f32_16x16x32_f16(aF, bF, acc[ct], 0, 0, 0);
        }
    }
#pragma unroll
    for (int ct = 0; ct < 4; ++ct) {
        int c = ct * 16 + lr;
        float asc = aS[c], adc = aD[c];
#pragma unroll
        for (int i = 0; i < 4; ++i) {
            int n = n0 + m0 + lg * 4 + i;
            float v = acc[ct][i];
            float s = v * asc, d = v * adc;
            s += __shfl_xor(s, 1, 64); s += __shfl_xor(s, 2, 64); s += __shfl_xor(s, 4, 64);
            d += __shfl_xor(d, 1, 64); d += __shfl_xor(d, 2, 64); d += __shfl_xor(d, 4, 64);
            if (n < N) {
                h1h[(size_t)n * 64 + c] = __float2half(v);
                if ((l & 7) == 0) {
                    int hd = 2 * ct + ((l >> 3) & 1);
                    as1[n * 8 + hd] = s;
                    ad1[n * 8 + hd] = d;
                }
            }
        }
    }
}

// ---------------- CSR build: binned counting sort ----------------
__global__ __launch_bounds__(256) void binhist(
    const int* __restrict__ dsts, int* __restrict__ bincnt, int E, int Et, int nbins)
{
    __shared__ int lh[MAXBINS];
    int t = threadIdx.x;
    for (int i = t; i < nbins; i += 256) lh[i] = 0;
    __syncthreads();
    int base = blockIdx.x * CHUNK;
#pragma unroll
    for (int r = 0; r < CHUNK / 256; ++r) {
        int i = base + r * 256 + t;
        if (i < Et) {
            int dn = (i < E) ? dsts[i] : (i - E);
            atomicAdd(&lh[dn >> BIN_SHIFT], 1);
        }
    }
    __syncthreads();
    for (int i = t; i < nbins; i += 256)
        if (lh[i]) atomicAdd(&bincnt[i], lh[i]);
}

__global__ void binscan(const int* __restrict__ bincnt, int* __restrict__ binoff,
                        int* __restrict__ bincur, int* __restrict__ row_ptr,
                        int nbins, int N, int Et)
{
    if (threadIdx.x == 0 && blockIdx.x == 0) {
        int run = 0;
        for (int b = 0; b < nbins; ++b) { binoff[b] = run; bincur[b] = run; run += bincnt[b]; }
        binoff[nbins] = run;
        row_ptr[N] = Et;
    }
}

__global__ __launch_bounds__(256) void binscatter(
    const int* __restrict__ srcs, const int* __restrict__ dsts,
    int* __restrict__ bincur, unsigned int* __restrict__ binned, int E, int Et, int nbins)
{
    __shared__ int lh[MAXBINS];
    __shared__ int gbase[MAXBINS];
    __shared__ int lcur[MAXBINS];
    int t = threadIdx.x;
    for (int i = t; i < nbins; i += 256) lh[i] = 0;
    __syncthreads();
    int base = blockIdx.x * CHUNK;
#pragma unroll
    for (int r = 0; r < CHUNK / 256; ++r) {
        int i = base + r * 256 + t;
        if (i < Et) {
            int dn = (i < E) ? dsts[i] : (i - E);
            atomicAdd(&lh[dn >> BIN_SHIFT], 1);
        }
    }
    __syncthreads();
    for (int i = t; i < nbins; i += 256) {
        gbase[i] = lh[i] ? atomicAdd(&bincur[i], lh[i]) : 0;
        lcur[i] = 0;
    }
    __syncthreads();
#pragma unroll
    for (int r = 0; r < CHUNK / 256; ++r) {
        int i = base + r * 256 + t;
        if (i < Et) {
            int s, dn;
            if (i < E) { s = srcs[i]; dn = dsts[i]; }
            else       { s = i - E;   dn = s; }
            int b = dn >> BIN_SHIFT;
            int li = atomicAdd(&lcur[b], 1);
            binned[gbase[b] + li] = ((unsigned)(dn & (NODES_PER_BIN - 1)) << 24) | (unsigned)s;
        }
    }
}

__global__ __launch_bounds__(256) void binsort(
    const unsigned int* __restrict__ binned, const int* __restrict__ binoff,
    int* __restrict__ row_ptr, int* __restrict__ colx, int N, int nbins)
{
    __shared__ int lh[NODES_PER_BIN];
    __shared__ int lcur[NODES_PER_BIN];
    int b = blockIdx.x, t = threadIdx.x;
    int beg = binoff[b], end = binoff[b + 1];
    lh[t] = 0;
    __syncthreads();
    for (int j = beg + t; j < end; j += 256)
        atomicAdd(&lh[binned[j] >> 24], 1);
    __syncthreads();
    int own = lh[t];
    for (int off = 1; off < 256; off <<= 1) {
        int y = (t >= off) ? lh[t - off] : 0;
        __syncthreads();
        lh[t] += y;
        __syncthreads();
    }
    int excl = lh[t] - own;
    int gnode = (b << BIN_SHIFT) + t;
    if (gnode < N) row_ptr[gnode] = beg + excl;
    lcur[t] = excl;
    __syncthreads();
    for (int j = beg + t; j < end; j += 256) {
        unsigned p = binned[j];
        int pos = atomicAdd(&lcur[p >> 24], 1);
        colx[beg + pos] = (int)(p & 0xFFFFFF);
    }
}

// ---------------- Layer 1 gather: 2 edges/wave, buffer loads, unroll-2 ----------------
__global__ __launch_bounds__(256) void gather1(
    const int* __restrict__ row_ptr, const int* __restrict__ colx,
    const float* __restrict__ as1, const float* __restrict__ ad1,
    const __half2* __restrict__ h1v, const float2* __restrict__ bias1,
    float2* __restrict__ helu, int N)
{
    int wave = (blockIdx.x * 256 + threadIdx.x) >> 6;
    if (wave >= N) return;
    int lane = threadIdx.x & 63;
    int half = lane >> 5;
    int sub = lane & 31;          // owns dims 2*sub, 2*sub+1
    int hh = sub >> 2;            // head of those dims
    int sub4 = sub << 2;
    int hh4 = hh << 2;
    v4i rsH = make_rsrc(h1v, (unsigned)N * 128u);
    v4i rsA = make_rsrc(as1, (unsigned)N * 32u);
    int n = wave;
    float adn = ad1[n * 8 + hh];
    int beg = row_ptr[n], end = row_ptr[n + 1];
    float2 acc = make_float2(0.f, 0.f);
    float wsum = 0.f;

#define G1_BODY(ii) { \
    int k0 = ((ii) << 2) + half; \
    int k1 = k0 + 2; \
    int sA = __shfl(sv, k0, 64); \
    int sB = __shfl(sv, k1, 64); \
    float aA = buf_load_f32(rsA, (sA << 5) + hh4, 0, 0); \
    float aB = buf_load_f32(rsA, (sB << 5) + hh4, 0, 0); \
    int ha = buf_load_i32(rsH, (sA << 7) + sub4, 0, 0); \
    int hb = buf_load_i32(rsH, (sB << 7) + sub4, 0, 0); \
    float eA = aA + adn; eA = fmaxf(eA, NEG_SLOPE * eA); \
    float eB = aB + adn; eB = fmaxf(eB, NEG_SLOPE * eB); \
    float wA = (k0 < cnt) ? __expf(eA) : 0.f; \
    float wB = (k1 < cnt) ? __expf(eB) : 0.f; \
    union { int i; __half2 h; } uA, uB; uA.i = ha; uB.i = hb; \
    float2 fA = __half22float2(uA.h); \
    float2 fB = __half22float2(uB.h); \
    acc.x = fmaf(wA, fA.x, acc.x); \
    acc.y = fmaf(wA, fA.y, acc.y); \
    acc.x = fmaf(wB, fB.x, acc.x); \
    acc.y = fmaf(wB, fB.y, acc.y); \
    wsum += wA + wB; }

    for (int cb = beg; cb < end; cb += 64) {
        int cnt = min(64, end - cb);
        int sv = (cb + lane < end) ? colx[cb + lane] : 0;
        int iters = (cnt + 3) >> 2;   // uniform across wave
        int i = 0;
        for (; i + 2 <= iters; i += 2) { G1_BODY(i) G1_BODY(i + 1) }
        for (; i < iters; ++i) { G1_BODY(i) }
    }
#undef G1_BODY

    acc.x += __shfl_xor(acc.x, 32, 64);
    acc.y += __shfl_xor(acc.y, 32, 64);
    wsum += __shfl_xor(wsum, 32, 64);
    if (half == 0) {
        float2 b = bias1[sub];
        float inv = 1.f / (wsum + EPSV);
        float vx = acc.x * inv + b.x;
        float vy = acc.y * inv + b.y;
        vx = (vx > 0.f) ? vx : (__expf(vx) - 1.f);
        vy = (vy > 0.f) ? vy : (__expf(vy) - 1.f);
        helu[(size_t)n * 32 + sub] = make_float2(vx, vy);
    }
}

// ---------------- Layer 2 GEMM via MFMA: h2 = helu@W2 (N,64)->(N,40) + scalar alphas ----------------
// h2h row stride padded to 64 halves (128B) for single-shift buffer addressing in gather2.
__global__ __launch_bounds__(256) void gemm2_alpha(
    const float* __restrict__ helu, const float* __restrict__ W2,
    const float* __restrict__ aS, const float* __restrict__ aD,
    __half* __restrict__ h2h, float* __restrict__ as2, float* __restrict__ ad2, int N)
{
    __shared__ _Float16 xh[64 * 64];    // 8 KB
    __shared__ _Float16 wt[48 * 64];    // 6 KB (rows 40..47 zero)
    int t = threadIdx.x;
    int n0 = blockIdx.x * 64;

    for (int i = t; i < (48 * 64) / 2; i += 256) ((uint32_t*)wt)[i] = 0;
    __syncthreads();

    const float2* h2p = (const float2*)helu;
#pragma unroll
    for (int i = 0; i < 8; ++i) {
        int p = t + i * 256;            // pairs over 64*32
        int n = p >> 5, kp = p & 31;
        int gn = n0 + n;
        float2 v = (gn < N) ? h2p[(size_t)gn * 32 + kp] : make_float2(0.f, 0.f);
        union { _Float16 h[2]; uint32_t u; } cv;
        cv.h[0] = (_Float16)v.x; cv.h[1] = (_Float16)v.y;
        *(uint32_t*)&xh[n * 64 + ((kp * 2) ^ ((n & 7) << 3))] = cv.u;
    }
#pragma unroll
    for (int i = 0; i < 10; ++i) {
        int p = t + i * 256;
        if (p < 64 * 40) {
            int k = p / 40, c = p - k * 40;
            wt[c * 64 + (k ^ ((c & 7) << 3))] = (_Float16)W2[p];
        }
    }
    __syncthreads();

    int wv = t >> 6, l = t & 63;
    int m0 = wv * 16;
    int lr = l & 15;
    int lg = l >> 4;
    float4v acc[3];
#pragma unroll
    for (int ct = 0; ct < 3; ++ct) acc[ct] = (float4v)(0.f);
#pragma unroll
    for (int kt = 0; kt < 2; ++kt) {
        int kh0 = kt * 32 + lg * 8;
        int an = m0 + lr;
        half8v aF = *(half8v*)&xh[an * 64 + (kh0 ^ ((an & 7) << 3))];
#pragma unroll
        for (int ct = 0; ct < 3; ++ct) {
            int c = ct * 16 + lr;
            half8v bF = *(half8v*)&wt[c * 64 + (kh0 ^ ((c & 7) << 3))];
            acc[ct] = __builtin_amdgcn_mfma_f32_16x16x32_f16(aF, bF, acc[ct], 0, 0, 0);
        }
    }
    float sv[4] = {0.f, 0.f, 0.f, 0.f};
    float dv[4] = {0.f, 0.f, 0.f, 0.f};
#pragma unroll
    for (int ct = 0; ct < 3; ++ct) {
        int c = ct * 16 + lr;
        bool av = (c < 40);
        float asc = av ? aS[c] : 0.f;
        float adc = av ? aD[c] : 0.f;
#pragma unroll
        for (int i = 0; i < 4; ++i) {
            int n = n0 + m0 + lg * 4 + i;
            float v = acc[ct][i];
            sv[i] = fmaf(v, asc, sv[i]);
            dv[i] = fmaf(v, adc, dv[i]);
            if (av && n < N) h2h[(size_t)n * 64 + c] = __float2half(v);
        }
    }
#pragma unroll
    for (int i = 0; i < 4; ++i) {
        float s = sv[i], d = dv[i];
        s += __shfl_xor(s, 1, 64); s += __shfl_xor(s, 2, 64);
        s += __shfl_xor(s, 4, 64); s += __shfl_xor(s, 8, 64);
        d += __shfl_xor(d, 1, 64); d += __shfl_xor(d, 2, 64);
        d += __shfl_xor(d, 4, 64); d += __shfl_xor(d, 8, 64);
        int n = n0 + m0 + lg * 4 + i;
        if (lr == 0 && n < N) { as2[n] = s; ad2[n] = d; }
    }
}

// ---------------- Layer 2 gather: 2 edges/wave, buffer loads, unroll-2 ----------------
__global__ __launch_bounds__(256) void gather2(
    const int* __restrict__ row_ptr, const int* __restrict__ colx,
    const float* __restrict__ as2, const float* __restrict__ ad2,
    const __half2* __restrict__ h2v, const float2* __restrict__ bias2,
    float2* __restrict__ out, int N)
{
    int wave = (blockIdx.x * 256 + threadIdx.x) >> 6;
    if (wave >= N) return;
    int lane = threadIdx.x & 63;
    int half = lane >> 5;
    int sub = lane & 31;          // owns dims 2*sub, 2*sub+1 (sub<20 active)
    bool act = (sub < 20);
    int subc4 = (act ? sub : 0) << 2;
    v4i rsH = make_rsrc(h2v, (unsigned)N * 128u);
    v4i rsA = make_rsrc(as2, (unsigned)N * 4u);
    int n = wave;
    float adn = ad2[n];
    int beg = row_ptr[n], end = row_ptr[n + 1];
    float2 acc = make_float2(0.f, 0.f);
    float wsum = 0.f;

#define G2_BODY(ii) { \
    int k0 = ((ii) << 2) + half; \
    int k1 = k0 + 2; \
    int sA = __shfl(sv, k0, 64); \
    int sB = __shfl(sv, k1, 64); \
    float aA = buf_load_f32(rsA, sA << 2, 0, 0); \
    float aB = buf_load_f32(rsA, sB << 2, 0, 0); \
    int ha = buf_load_i32(rsH, (sA << 7) + subc4, 0, 0); \
    int hb = buf_load_i32(rsH, (sB << 7) + subc4, 0, 0); \
    float eA = aA + adn; eA = fmaxf(eA, NEG_SLOPE * eA); \
    float eB = aB + adn; eB = fmaxf(eB, NEG_SLOPE * eB); \
    float wA = (k0 < cnt) ? __expf(eA) : 0.f; \
    float wB = (k1 < cnt) ? __expf(eB) : 0.f; \
    union { int i; __half2 h; } uA, uB; uA.i = ha; uB.i = hb; \
    float2 fA = __half22float2(uA.h); \
    float2 fB = __half22float2(uB.h); \
    acc.x = fmaf(wA, fA.x, acc.x); \
    acc.y = fmaf(wA, fA.y, acc.y); \
    acc.x = fmaf(wB, fB.x, acc.x); \
    acc.y = fmaf(wB, fB.y, acc.y); \
    wsum += wA + wB; }

    for (int cb = beg; cb < end; cb += 64) {
        int cnt = min(64, end - cb);
        int sv = (cb + lane < end) ? colx[cb + lane] : 0;
        int iters = (cnt + 3) >> 2;   // uniform across wave
        int i = 0;
        for (; i + 2 <= iters; i += 2) { G2_BODY(i) G2_BODY(i + 1) }
        for (; i < iters; ++i) { G2_BODY(i) }
    }
#undef G2_BODY

    acc.x += __shfl_xor(acc.x, 32, 64);
    acc.y += __shfl_xor(acc.y, 32, 64);
    wsum += __shfl_xor(wsum, 32, 64);
    if (half == 0 && act) {
        float2 b = bias2[sub];
        float inv = 1.f / (wsum + EPSV);
        out[(size_t)n * 20 + sub] = make_float2(acc.x * inv + b.x, acc.y * inv + b.y);
    }
}

extern "C" void kernel_launch(void* const* d_in, const int* in_sizes, int n_in,
                              void* d_out, int out_size, void* d_ws, size_t ws_size,
                              hipStream_t stream)
{
    const float* x   = (const float*)d_in[0];
    const int*   ei  = (const int*)d_in[1];
    const float* W1  = (const float*)d_in[3];
    const float* aS1 = (const float*)d_in[4];
    const float* aD1 = (const float*)d_in[5];
    const float* b1  = (const float*)d_in[6];
    const float* W2  = (const float*)d_in[7];
    const float* aS2 = (const float*)d_in[8];
    const float* aD2 = (const float*)d_in[9];
    const float* b2  = (const float*)d_in[10];

    int N  = in_sizes[0] / 128;
    int E  = in_sizes[1] / 2;
    int Et = E + N;
    int nbins = (N + NODES_PER_BIN - 1) >> BIN_SHIFT;

    // ---- workspace layout ----
    float* fws   = (float*)d_ws;
    float* as1   = fws;                        // N*8
    float* ad1   = as1  + (size_t)N * 8;       // N*8
    float* helu  = ad1  + (size_t)N * 8;       // N*64
    float* as2   = helu + (size_t)N * 64;      // N
    float* ad2   = as2  + (size_t)N;           // N
    __half* h1h  = (__half*)(ad2 + (size_t)N); // N*64 halves
    __half* h2h  = h1h + (size_t)N * 64;       // N*64 halves (stride-64 padded)
    int*   iws     = (int*)(h2h + (size_t)N * 64);
    int*   row_ptr = iws;                      // N+1
    int*   bincnt  = row_ptr + N + 1;          // MAXBINS+1
    int*   binoff  = bincnt + MAXBINS + 1;     // MAXBINS+1
    int*   bincur  = binoff + MAXBINS + 1;     // MAXBINS
    unsigned int* binned = (unsigned int*)(bincur + MAXBINS);  // Et
    int*   colx    = (int*)(binned + Et);      // Et
    float* out     = (float*)d_out;

    const int* srcs = ei;
    const int* dsts = ei + E;

    int blocksA = (Et + CHUNK - 1) / CHUNK;

    // ---- CSR build (binned counting sort) ----
    hipMemsetAsync(bincnt, 0, (size_t)(MAXBINS + 1) * sizeof(int), stream);
    binhist<<<blocksA, 256, 0, stream>>>(dsts, bincnt, E, Et, nbins);
    binscan<<<1, 64, 0, stream>>>(bincnt, binoff, bincur, row_ptr, nbins, N, Et);
    binscatter<<<blocksA, 256, 0, stream>>>(srcs, dsts, bincur, binned, E, Et, nbins);
    binsort<<<nbins, 256, 0, stream>>>(binned, binoff, row_ptr, colx, N, nbins);

    // ---- Layer 1 ----
    gemm1_alpha<<<(N + 63) / 64, 256, 0, stream>>>(x, W1, aS1, aD1, h1h, as1, ad1, N);
    gather1<<<(N * 64 + 255) / 256, 256, 0, stream>>>(row_ptr, colx, as1, ad1,
        (const __half2*)h1h, (const float2*)b1, (float2*)helu, N);

    // ---- Layer 2 ----
    gemm2_alpha<<<(N + 63) / 64, 256, 0, stream>>>(helu, W2, aS2, aD2, h2h, as2, ad2, N);
    gather2<<<(N * 64 + 255) / 256, 256, 0, stream>>>(row_ptr, colx, as2, ad2,
        (const __half2*)h2h, (const float2*)b2, (float2*)out, N);
}